// Round 1
// baseline (210.536 us; speedup 1.0000x reference)
//
#include <hip/hip_runtime.h>
#include <hip/hip_bf16.h>
#include <math.h>

// Problem constants (fixed by the reference: B=8,S=2048,H=512,G=2,V=320,D=256)
constexpr int Mn = 16384;   // N = B*S rows
constexpr int Kd = 512;     // H
constexpr int GV = 640;     // G*V
constexpr int Vn = 320;     // V
constexpr int Gn = 2;       // G
constexpr int DG = 128;     // D/G
constexpr float EPSc = 1e-7f;

// ---------------- Kernel 1: fp32 GEMM  C[M,GV] = A[M,K] @ B[K,GV] + bias ----
// 64x64 tile, 256 threads, each thread a 4x4 microtile, BK=16, single-buffered.
__global__ __launch_bounds__(256) void gemm_bias(const float* __restrict__ A,
                                                 const float* __restrict__ B,
                                                 const float* __restrict__ bias,
                                                 float* __restrict__ C) {
  constexpr int BM = 64, BN = 64, BK = 16;
  __shared__ float As[BK][BM + 4];  // transposed A tile, +4 pad keeps 16B align
  __shared__ float Bs[BK][BN + 4];
  const int t = threadIdx.x;
  const int tx = t & 15, ty = t >> 4;
  const int m0 = blockIdx.y * BM, n0 = blockIdx.x * BN;
  const int aRow = t >> 2, aCol = (t & 3) * 4;   // A: 64 rows x 16 cols, float4 each
  const int bRow = t >> 4, bCol = (t & 15) * 4;  // B: 16 rows x 64 cols, float4 each

  float acc[4][4] = {};
  for (int k0 = 0; k0 < Kd; k0 += BK) {
    float4 av = *reinterpret_cast<const float4*>(&A[(size_t)(m0 + aRow) * Kd + k0 + aCol]);
    float4 bv = *reinterpret_cast<const float4*>(&B[(size_t)(k0 + bRow) * GV + n0 + bCol]);
    As[aCol + 0][aRow] = av.x;
    As[aCol + 1][aRow] = av.y;
    As[aCol + 2][aRow] = av.z;
    As[aCol + 3][aRow] = av.w;
    *reinterpret_cast<float4*>(&Bs[bRow][bCol]) = bv;
    __syncthreads();
#pragma unroll
    for (int kk = 0; kk < BK; ++kk) {
      float4 a4 = *reinterpret_cast<const float4*>(&As[kk][ty * 4]);
      float4 b4 = *reinterpret_cast<const float4*>(&Bs[kk][tx * 4]);
      float aa[4] = {a4.x, a4.y, a4.z, a4.w};
      float bb[4] = {b4.x, b4.y, b4.z, b4.w};
#pragma unroll
      for (int i = 0; i < 4; ++i)
#pragma unroll
        for (int j = 0; j < 4; ++j) acc[i][j] = fmaf(aa[i], bb[j], acc[i][j]);
    }
    __syncthreads();
  }
  const int col = n0 + tx * 4;
  float4 bz = *reinterpret_cast<const float4*>(&bias[col]);
#pragma unroll
  for (int i = 0; i < 4; ++i) {
    float4 o;
    o.x = acc[i][0] + bz.x;
    o.y = acc[i][1] + bz.y;
    o.z = acc[i][2] + bz.z;
    o.w = acc[i][3] + bz.w;
    *reinterpret_cast<float4*>(&C[(size_t)(m0 + ty * 4 + i) * GV + col]) = o;
  }
}

// ---------------- Kernel 2: per-row softmax stats + argmax gather + marginal -
// Block = 256 threads (4 waves). Block handles 32 rows. Wave w: group g = w&1,
// row stream = w>>1 (2 streams x 16 iters). Lane owns v = lane + 64*j, j<5.
__global__ __launch_bounds__(256) void row_kernel(const float* __restrict__ logits,
                                                  const float* __restrict__ gumbels,
                                                  const int* __restrict__ mask,
                                                  const float* __restrict__ codevectors,
                                                  float* __restrict__ out,
                                                  float* __restrict__ marg_global) {
  __shared__ float marg[GV];
  const int t = threadIdx.x;
  for (int i = t; i < GV; i += 256) marg[i] = 0.f;
  __syncthreads();

  const int wave = t >> 6, lane = t & 63;
  const int g = wave & 1;
  const int nstream = wave >> 1;
  const int nbase = blockIdx.x * 32;

  float acc[5] = {0.f, 0.f, 0.f, 0.f, 0.f};

  for (int it = 0; it < 16; ++it) {
    const int n = nbase + nstream * 16 + it;
    const float* lrow = logits + (size_t)n * GV + g * Vn;
    const float* grow = gumbels + ((size_t)n * Gn + g) * Vn;

    float vals[5];
    float fmaxv = -INFINITY;
    float amax = -INFINITY;
    int aidx = 0;
#pragma unroll
    for (int j = 0; j < 5; ++j) {
      const int v = lane + 64 * j;
      const float x = lrow[v];
      vals[j] = x;
      const float y = x + grow[v];
      fmaxv = fmaxf(fmaxv, x);
      if (y > amax) { amax = y; aidx = v; }  // strict > keeps lowest index (np tie rule)
    }
    // wave-wide reduce: max(flat) and argmax(flat+gumbel)
#pragma unroll
    for (int off = 32; off; off >>= 1) {
      fmaxv = fmaxf(fmaxv, __shfl_xor(fmaxv, off));
      const float oa = __shfl_xor(amax, off);
      const int oi = __shfl_xor(aidx, off);
      if (oa > amax || (oa == amax && oi < aidx)) { amax = oa; aidx = oi; }
    }
    float e[5], sum = 0.f;
#pragma unroll
    for (int j = 0; j < 5; ++j) {
      e[j] = expf(vals[j] - fmaxv);
      sum += e[j];
    }
#pragma unroll
    for (int off = 32; off; off >>= 1) sum += __shfl_xor(sum, off);
    const float inv = 1.0f / sum;

    if (mask[n] != 0) {
#pragma unroll
      for (int j = 0; j < 5; ++j) acc[j] += e[j] * inv;
    }

    // codevector gather: out[n, g*128 .. g*128+127] = codevectors[g*V + aidx, :]
    const float* cv = codevectors + ((size_t)g * Vn + aidx) * DG;
    float* orow = out + (size_t)n * (Gn * DG) + g * DG;
    orow[lane] = cv[lane];
    orow[lane + 64] = cv[lane + 64];
  }

  // per-wave register partials -> LDS
#pragma unroll
  for (int j = 0; j < 5; ++j) atomicAdd(&marg[g * Vn + lane + 64 * j], acc[j]);
  __syncthreads();
  for (int i = t; i < GV; i += 256) atomicAdd(&marg_global[i], marg[i]);
}

// ---------------- Kernel 3: perplexity from marginal --------------------------
__global__ __launch_bounds__(256) void finalize(const float* __restrict__ marg_global,
                                                const int* __restrict__ mask,
                                                float* __restrict__ out_pp) {
  __shared__ float red[256];
  const int t = threadIdx.x;
  float s = 0.f;
  for (int i = t; i < Mn; i += 256) s += (float)mask[i];
  red[t] = s;
  __syncthreads();
  for (int o = 128; o; o >>= 1) {
    if (t < o) red[t] += red[t + o];
    __syncthreads();
  }
  const float summ = red[0];
  __syncthreads();

  float pp = 0.f;
  for (int g = 0; g < Gn; ++g) {
    float e = 0.f;
    for (int i = t; i < Vn; i += 256) {
      const float p = marg_global[g * Vn + i] / summ;
      e += p * logf(p + EPSc);
    }
    red[t] = e;
    __syncthreads();
    for (int o = 128; o; o >>= 1) {
      if (t < o) red[t] += red[t + o];
      __syncthreads();
    }
    pp += expf(-red[0]);
    __syncthreads();
  }
  if (t == 0) out_pp[0] = pp;
}

extern "C" void kernel_launch(void* const* d_in, const int* in_sizes, int n_in,
                              void* d_out, int out_size, void* d_ws, size_t ws_size,
                              hipStream_t stream) {
  const float* hidden      = (const float*)d_in[0];  // [16384, 512]
  const int*   mask        = (const int*)d_in[1];    // [16384]
  const float* W           = (const float*)d_in[2];  // [512, 640]
  const float* bias        = (const float*)d_in[3];  // [640]
  const float* codevectors = (const float*)d_in[4];  // [640, 128]
  const float* gumbels     = (const float*)d_in[5];  // [32768, 320]
  float* out = (float*)d_out;                        // 16384*256 codevecs + 1 perplexity

  float* logits = (float*)d_ws;                                     // 40 MB
  float* marg   = (float*)((char*)d_ws + (size_t)Mn * GV * sizeof(float));  // 640 f32

  hipMemsetAsync(marg, 0, GV * sizeof(float), stream);

  dim3 g1(GV / 64, Mn / 64);  // (10, 256)
  gemm_bias<<<g1, 256, 0, stream>>>(hidden, W, bias, logits);

  row_kernel<<<Mn / 32, 256, 0, stream>>>(logits, gumbels, mask, codevectors, out, marg);

  finalize<<<1, 256, 0, stream>>>(marg, mask, out + (size_t)Mn * (Gn * DG));
}

// Round 2
// 137.917 us; speedup vs baseline: 1.5265x; 1.5265x over previous
//
#include <hip/hip_runtime.h>
#include <hip/hip_bf16.h>
#include <math.h>

// Problem constants (fixed by the reference: B=8,S=2048,H=512,G=2,V=320,D=256)
constexpr int Mn = 16384;   // N = B*S rows
constexpr int Kd = 512;     // H
constexpr int GV = 640;     // G*V
constexpr int Vn = 320;     // V
constexpr int Gn = 2;       // G
constexpr int DG = 128;     // D/G
constexpr float EPSc = 1e-7f;

constexpr int K2 = 1536;    // split GEMM K' = 3*Kd
constexpr int KA = 1024;    // A2 width = 2*Kd (planes h0,h1)

typedef _Float16 half8 __attribute__((ext_vector_type(8)));
typedef _Float16 half4 __attribute__((ext_vector_type(4)));
typedef float floatx4 __attribute__((ext_vector_type(4)));

// ---------------- fp32 -> 2x fp16 split converters ---------------------------
// A2[m][0..511] = h0, A2[m][512..1023] = h1   (h = h0 + h1 + O(2^-22))
__global__ __launch_bounds__(256) void convert_hidden(const float* __restrict__ h,
                                                      _Float16* __restrict__ A2) {
  const int total = Mn * Kd / 4;  // float4 count
  for (int idx = blockIdx.x * 256 + threadIdx.x; idx < total; idx += 2048 * 256) {
    float4 x = reinterpret_cast<const float4*>(h)[idx];
    int m = idx >> 7;           // 128 float4 per row
    int c = (idx & 127) << 2;
    half4 h0, h1;
    float xs[4] = {x.x, x.y, x.z, x.w};
#pragma unroll
    for (int j = 0; j < 4; ++j) {
      _Float16 a = (_Float16)xs[j];
      h0[j] = a;
      h1[j] = (_Float16)(xs[j] - (float)a);
    }
    *reinterpret_cast<half4*>(&A2[(size_t)m * KA + c]) = h0;
    *reinterpret_cast<half4*>(&A2[(size_t)m * KA + Kd + c]) = h1;
  }
}

// B2T[n][k']  (n=0..639, k'=0..1535): [w0 | w0 | w1] transposed (k-contiguous)
__global__ __launch_bounds__(256) void convert_W(const float* __restrict__ W,
                                                 _Float16* __restrict__ B2T) {
  int idx = blockIdx.x * 256 + threadIdx.x;  // 512*640 total
  if (idx >= Kd * GV) return;
  int k = idx / GV, n = idx % GV;
  float w = W[idx];
  _Float16 w0 = (_Float16)w;
  _Float16 w1 = (_Float16)(w - (float)w0);
  _Float16* row = B2T + (size_t)n * K2;
  row[k] = w0;
  row[Kd + k] = w0;
  row[2 * Kd + k] = w1;
}

// ---------------- MFMA GEMM: C[16384,640] = A'(fp16 split) @ B' + bias -------
// BM=128, BN=64, BK=32; 1280 blocks (5/CU exactly); 4 waves in 2x2;
// wave tile 64x32 -> 4x2 frags of 16x16; mfma_f32_16x16x32_f16.
__global__ __launch_bounds__(256) void gemm_f16x2(const _Float16* __restrict__ A2,
                                                  const _Float16* __restrict__ B2T,
                                                  const float* __restrict__ bias,
                                                  float* __restrict__ C) {
  __shared__ _Float16 As[128 * 32];  // 8 KB, row-major [r][k]
  __shared__ _Float16 Bs[64 * 32];   // 4 KB, row-major [n][k] (B^T tile)

  // XCD-chunked swizzle: 1280 blocks, 160/XCD; within an XCD the 10 N-tiles of
  // one A-panel are consecutive -> A-panel stays in that XCD's L2.
  const int bid = blockIdx.x;
  const int sw = (bid & 7) * 160 + (bid >> 3);
  const int mt = sw / 10, nt = sw % 10;
  const int m0 = mt * 128, n0 = nt * 64;

  const int t = threadIdx.x, wv = t >> 6, l = t & 63;
  const int wr = wv >> 1, wc = wv & 1;     // wave tile: rows wr*64, cols wc*32
  const int lr = l & 15, lk = l >> 4;

  floatx4 acc[4][2] = {};

  for (int kt = 0; kt < K2 / 32; ++kt) {
    const int k2 = kt * 32;
    const int kA = k2 >= KA ? k2 - KA : k2;  // fold third pass onto plane h0

    // stage A: 128x32 halves = 512 x 16B; thread does 2 loads
#pragma unroll
    for (int i = 0; i < 2; ++i) {
      const int idx = i * 256 + wv * 64 + l;          // 0..511
      const int r = idx >> 2, p = idx & 3;
      const _Float16* ga = A2 + (size_t)(m0 + r) * KA + kA + p * 8;
      _Float16* la = As + (size_t)(i * 256 + wv * 64) * 8;  // wave-uniform base
      __builtin_amdgcn_global_load_lds((const __attribute__((address_space(1))) void*)ga,
                                       (__attribute__((address_space(3))) void*)la, 16, 0, 0);
    }
    // stage B: 64x32 halves = 256 x 16B; thread does 1 load
    {
      const int idx = wv * 64 + l;                    // 0..255
      const int r = idx >> 2, p = idx & 3;
      const _Float16* gb = B2T + (size_t)(n0 + r) * K2 + k2 + p * 8;
      _Float16* lb = Bs + (size_t)(wv * 64) * 8;
      __builtin_amdgcn_global_load_lds((const __attribute__((address_space(1))) void*)gb,
                                       (__attribute__((address_space(3))) void*)lb, 16, 0, 0);
    }
    __syncthreads();  // drains vmcnt before barrier (compiler-enforced)

    half8 af[4], bf[2];
#pragma unroll
    for (int mi = 0; mi < 4; ++mi)
      af[mi] = *reinterpret_cast<const half8*>(&As[(wr * 64 + mi * 16 + lr) * 32 + lk * 8]);
#pragma unroll
    for (int ni = 0; ni < 2; ++ni)
      bf[ni] = *reinterpret_cast<const half8*>(&Bs[(wc * 32 + ni * 16 + lr) * 32 + lk * 8]);
#pragma unroll
    for (int mi = 0; mi < 4; ++mi)
#pragma unroll
      for (int ni = 0; ni < 2; ++ni)
        acc[mi][ni] = __builtin_amdgcn_mfma_f32_16x16x32_f16(af[mi], bf[ni], acc[mi][ni], 0, 0, 0);
    __syncthreads();
  }

  // epilogue: C/D layout col = l&15, row = (l>>4)*4 + j
#pragma unroll
  for (int ni = 0; ni < 2; ++ni) {
    const int gcol = n0 + wc * 32 + ni * 16 + lr;
    const float bv = bias[gcol];
#pragma unroll
    for (int mi = 0; mi < 4; ++mi) {
      const int grow = m0 + wr * 64 + mi * 16 + lk * 4;
#pragma unroll
      for (int j = 0; j < 4; ++j)
        C[(size_t)(grow + j) * GV + gcol] = acc[mi][ni][j] + bv;
    }
  }
}

// ---------------- fallback fp32 GEMM (used only if ws too small) -------------
__global__ __launch_bounds__(256) void gemm_bias(const float* __restrict__ A,
                                                 const float* __restrict__ B,
                                                 const float* __restrict__ bias,
                                                 float* __restrict__ C) {
  constexpr int BM = 64, BN = 64, BK = 16;
  __shared__ float As[BK][BM + 4];
  __shared__ float Bs[BK][BN + 4];
  const int t = threadIdx.x;
  const int tx = t & 15, ty = t >> 4;
  const int m0 = blockIdx.y * BM, n0 = blockIdx.x * BN;
  const int aRow = t >> 2, aCol = (t & 3) * 4;
  const int bRow = t >> 4, bCol = (t & 15) * 4;

  float acc[4][4] = {};
  for (int k0 = 0; k0 < Kd; k0 += BK) {
    float4 av = *reinterpret_cast<const float4*>(&A[(size_t)(m0 + aRow) * Kd + k0 + aCol]);
    float4 bv = *reinterpret_cast<const float4*>(&B[(size_t)(k0 + bRow) * GV + n0 + bCol]);
    As[aCol + 0][aRow] = av.x;
    As[aCol + 1][aRow] = av.y;
    As[aCol + 2][aRow] = av.z;
    As[aCol + 3][aRow] = av.w;
    *reinterpret_cast<float4*>(&Bs[bRow][bCol]) = bv;
    __syncthreads();
#pragma unroll
    for (int kk = 0; kk < BK; ++kk) {
      float4 a4 = *reinterpret_cast<const float4*>(&As[kk][ty * 4]);
      float4 b4 = *reinterpret_cast<const float4*>(&Bs[kk][tx * 4]);
      float aa[4] = {a4.x, a4.y, a4.z, a4.w};
      float bb[4] = {b4.x, b4.y, b4.z, b4.w};
#pragma unroll
      for (int i = 0; i < 4; ++i)
#pragma unroll
        for (int j = 0; j < 4; ++j) acc[i][j] = fmaf(aa[i], bb[j], acc[i][j]);
    }
    __syncthreads();
  }
  const int col = n0 + tx * 4;
  float4 bz = *reinterpret_cast<const float4*>(&bias[col]);
#pragma unroll
  for (int i = 0; i < 4; ++i) {
    float4 o;
    o.x = acc[i][0] + bz.x;
    o.y = acc[i][1] + bz.y;
    o.z = acc[i][2] + bz.z;
    o.w = acc[i][3] + bz.w;
    *reinterpret_cast<float4*>(&C[(size_t)(m0 + ty * 4 + i) * GV + col]) = o;
  }
}

// ---------------- per-row softmax stats + argmax gather + marginal -----------
// Block = 256 threads (4 waves), 32 rows/block. Wave w: group g=w&1, row
// stream w>>1. Lane owns v = lane + 64*j, j<5. Also accumulates mask count
// into marg_global[640].
__global__ __launch_bounds__(256) void row_kernel(const float* __restrict__ logits,
                                                  const float* __restrict__ gumbels,
                                                  const int* __restrict__ mask,
                                                  const float* __restrict__ codevectors,
                                                  float* __restrict__ out,
                                                  float* __restrict__ marg_global) {
  __shared__ float marg[GV];
  const int t = threadIdx.x;
  for (int i = t; i < GV; i += 256) marg[i] = 0.f;
  __syncthreads();

  const int wave = t >> 6, lane = t & 63;
  const int g = wave & 1;
  const int nstream = wave >> 1;
  const int nbase = blockIdx.x * 32;

  float acc[5] = {0.f, 0.f, 0.f, 0.f, 0.f};
  int cnt = 0;

  for (int it = 0; it < 16; ++it) {
    const int n = nbase + nstream * 16 + it;
    const float* lrow = logits + (size_t)n * GV + g * Vn;
    const float* grow = gumbels + ((size_t)n * Gn + g) * Vn;

    float vals[5];
    float fmaxv = -INFINITY;
    float amax = -INFINITY;
    int aidx = 0;
#pragma unroll
    for (int j = 0; j < 5; ++j) {
      const int v = lane + 64 * j;
      const float x = lrow[v];
      vals[j] = x;
      const float y = x + grow[v];
      fmaxv = fmaxf(fmaxv, x);
      if (y > amax) { amax = y; aidx = v; }  // strict > keeps lowest index
    }
#pragma unroll
    for (int off = 32; off; off >>= 1) {
      fmaxv = fmaxf(fmaxv, __shfl_xor(fmaxv, off));
      const float oa = __shfl_xor(amax, off);
      const int oi = __shfl_xor(aidx, off);
      if (oa > amax || (oa == amax && oi < aidx)) { amax = oa; aidx = oi; }
    }
    float e[5], sum = 0.f;
#pragma unroll
    for (int j = 0; j < 5; ++j) {
      e[j] = expf(vals[j] - fmaxv);
      sum += e[j];
    }
#pragma unroll
    for (int off = 32; off; off >>= 1) sum += __shfl_xor(sum, off);
    const float inv = 1.0f / sum;

    const int mk = mask[n];
    if (mk != 0) {
#pragma unroll
      for (int j = 0; j < 5; ++j) acc[j] += e[j] * inv;
    }
    if (g == 0 && lane == 0) cnt += (mk != 0);

    const float* cv = codevectors + ((size_t)g * Vn + aidx) * DG;
    float* orow = out + (size_t)n * (Gn * DG) + g * DG;
    orow[lane] = cv[lane];
    orow[lane + 64] = cv[lane + 64];
  }

#pragma unroll
  for (int j = 0; j < 5; ++j) atomicAdd(&marg[g * Vn + lane + 64 * j], acc[j]);
  if (g == 0 && lane == 0) atomicAdd(&marg_global[GV], (float)cnt);
  __syncthreads();
  for (int i = t; i < GV; i += 256) atomicAdd(&marg_global[i], marg[i]);
}

// ---------------- perplexity from marginal (mask count precomputed) ----------
__global__ __launch_bounds__(256) void finalize(const float* __restrict__ marg_global,
                                                float* __restrict__ out_pp) {
  __shared__ float red[256];
  const int t = threadIdx.x;
  const float summ = marg_global[GV];

  float pp = 0.f;
  for (int g = 0; g < Gn; ++g) {
    float e = 0.f;
    for (int i = t; i < Vn; i += 256) {
      const float p = marg_global[g * Vn + i] / summ;
      e += p * logf(p + EPSc);
    }
    red[t] = e;
    __syncthreads();
    for (int o = 128; o; o >>= 1) {
      if (t < o) red[t] += red[t + o];
      __syncthreads();
    }
    pp += expf(-red[0]);
    __syncthreads();
  }
  if (t == 0) out_pp[0] = pp;
}

extern "C" void kernel_launch(void* const* d_in, const int* in_sizes, int n_in,
                              void* d_out, int out_size, void* d_ws, size_t ws_size,
                              hipStream_t stream) {
  const float* hidden      = (const float*)d_in[0];  // [16384, 512]
  const int*   mask        = (const int*)d_in[1];    // [16384]
  const float* W           = (const float*)d_in[2];  // [512, 640]
  const float* bias        = (const float*)d_in[3];  // [640]
  const float* codevectors = (const float*)d_in[4];  // [640, 128]
  const float* gumbels     = (const float*)d_in[5];  // [32768, 320]
  float* out = (float*)d_out;                        // 16384*256 codevecs + 1 ppl

  // workspace layout (all offsets 256B-aligned)
  const size_t logitsBytes = (size_t)Mn * GV * sizeof(float);      // 41,943,040
  const size_t margOff     = logitsBytes;                          // 641 floats
  const size_t a2Off       = logitsBytes + 8192;
  const size_t a2Bytes     = (size_t)Mn * KA * sizeof(_Float16);   // 33,554,432
  const size_t b2tOff      = a2Off + a2Bytes;
  const size_t b2tBytes    = (size_t)GV * K2 * sizeof(_Float16);   //  1,966,080
  const size_t needBytes   = b2tOff + b2tBytes;

  float*    logits = (float*)d_ws;
  float*    marg   = (float*)((char*)d_ws + margOff);
  _Float16* A2     = (_Float16*)((char*)d_ws + a2Off);
  _Float16* B2T    = (_Float16*)((char*)d_ws + b2tOff);

  hipMemsetAsync(marg, 0, (GV + 1) * sizeof(float), stream);

  if (ws_size >= needBytes) {
    convert_hidden<<<2048, 256, 0, stream>>>(hidden, A2);
    convert_W<<<(Kd * GV + 255) / 256, 256, 0, stream>>>(W, B2T);
    gemm_f16x2<<<1280, 256, 0, stream>>>(A2, B2T, bias, logits);
  } else {
    dim3 g1(GV / 64, Mn / 64);
    gemm_bias<<<g1, 256, 0, stream>>>(hidden, W, bias, logits);
  }

  row_kernel<<<Mn / 32, 256, 0, stream>>>(logits, gumbels, mask, codevectors, out, marg);

  finalize<<<1, 256, 0, stream>>>(marg, out + (size_t)Mn * (Gn * DG));
}